// Round 7
// baseline (146.211 us; speedup 1.0000x reference)
//
#include <hip/hip_runtime.h>
#include <hip/hip_bf16.h>

// Chamfer loss, B=8, N=M=8192, D=3, fp32.
// result = (mean_n min_m d2(a_n,b_m) + mean_m min_n d2) / 2
// d2 = a2 + b2 - 2ab; track max_q where q = ab - 0.5*b2, then
// d2_min = max(a2 - 2*max_q, 0).
//
// R7: packed fp32 via inline-asm v_pk_fma_f32 (op_sel broadcast pulls b
// components straight from the LDS-loaded pair; compiler scalarizes v2f
// intrinsics, R4/R5). gfx950 has NO v_pk_max_f32 (R6 compile fail) — the
// max runs as component-wise v_max3_f32 on the packed halves instead:
// 6 pk_fma + 2 max3 per (a-pair, 2 b-points) = 2.0 inst/pair-product.

typedef float v2f __attribute__((ext_vector_type(2)));

// d = a*b + c with VOP3P half-select modifiers.
#define PK_FMA(d, a, b, c, mods) \
  asm("v_pk_fma_f32 %0, %1, %2, %3 " mods : "=v"(d) : "v"(a), "v"(b), "v"(c))

// src0 (a-pair) natural; src1/src2 broadcast per comment.
#define MODS_Z_NW "op_sel:[0,0,1] op_sel_hi:[1,0,1]"  // src1=lo(z) both, src2=hi(nw) both
#define MODS_Y    "op_sel:[0,1,0] op_sel_hi:[1,1,1]"  // src1=hi(y) both, src2 natural
#define MODS_X    "op_sel:[0,0,0] op_sel_hi:[1,0,1]"  // src1=lo(x) both, src2 natural

#define BATCH   8
#define NPTS    8192
#define BLK     256
#define TOTAL_A (2 * BATCH * NPTS)    // 131072
#define NCH     8                     // m-chunks across blocks
#define CH      (NPTS / NCH)          // 1024 b-points per block
#define CHW     (CH / 4)              // 256 b-points per wave
#define PPB     1024                  // a-points per block
#define NB      (NPTS / PPB)          // 8
#define GRID1   (2 * BATCH * NB * NCH)  // 1024
#define P2_BLOCKS (TOTAL_A / BLK)     // 512

__global__ __launch_bounds__(BLK, 4) void chamfer_pass1(
    const float* __restrict__ pred, const float* __restrict__ gt,
    float* __restrict__ partial, float* __restrict__ acc) {
  __shared__ float4 bs[CH];          // 16 KB: (x, y, z, -0.5|b|^2)
  __shared__ float  red[4 * PPB];    // 16 KB: per-wave maxes

  const int bid   = blockIdx.x;
  const int chunk = bid & (NCH - 1);
  const int r     = bid >> 3;
  const int nb    = r & (NB - 1);
  const int r2    = r >> 3;
  const int batch = r2 & (BATCH - 1);
  const int side  = r2 >> 3;

  const float* A  = (side == 0) ? pred : gt;
  const float* Bp = (side == 0) ? gt : pred;
  const int t = threadIdx.x;
  const int l = t & 63;
  const int w = t >> 6;

  if (bid == 0 && t == 0) {          // zero acc + counter for pass2
    acc[0] = 0.0f;
    ((unsigned*)acc)[1] = 0u;
  }

  // stage b-chunk (R3's measured-conflict-free pattern)
  const float* bbase = Bp + ((size_t)batch * NPTS + (size_t)chunk * CH) * 3;
  for (int p = t; p < CH; p += BLK) {
    float bx = bbase[p * 3 + 0];
    float by = bbase[p * 3 + 1];
    float bz = bbase[p * 3 + 2];
    bs[p] = make_float4(bx, by, bz,
                        -0.5f * fmaf(bx, bx, fmaf(by, by, bz * bz)));
  }

  // load 16 a-points as 8 packed pairs (same for every wave; L1-hot).
  // pair p = g*2+k holds points n_local = g*256 + l*4 + 2k + {0,1}
  v2f ax2[8], ay2[8], az2[8];
  float mq[16];
  const float* abase = A + ((size_t)batch * NPTS + (size_t)nb * PPB) * 3;
#pragma unroll
  for (int g = 0; g < 4; g++) {
    const float4* a4 = (const float4*)(abase + (size_t)(g * 256 + l * 4) * 3);
    float4 f0 = a4[0], f1 = a4[1], f2 = a4[2];
    ax2[g*2+0] = (v2f){f0.x, f0.w}; ay2[g*2+0] = (v2f){f0.y, f1.x}; az2[g*2+0] = (v2f){f0.z, f1.y};
    ax2[g*2+1] = (v2f){f1.z, f2.y}; ay2[g*2+1] = (v2f){f1.w, f2.z}; az2[g*2+1] = (v2f){f2.x, f2.w};
#pragma unroll
    for (int k = 0; k < 4; k++) mq[g*4+k] = -1e30f;
  }
  __syncthreads();

  // main loop: wave w covers b-points [w*CHW, (w+1)*CHW), 2 per iter.
  const v2f* bw = (const v2f*)(bs + w * CHW);   // [xy, zw] per point
  for (int j = 0; j < 2 * CHW; j += 4) {
    v2f b0xy = bw[j + 0], b0zw = bw[j + 1];
    v2f b1xy = bw[j + 2], b1zw = bw[j + 3];
#pragma unroll
    for (int p = 0; p < 8; p++) {
      v2f q0, q1;
      PK_FMA(q0, az2[p], b0zw, b0zw, MODS_Z_NW);   // az*z + nw
      PK_FMA(q0, ay2[p], b0xy, q0,   MODS_Y);      // + ay*y
      PK_FMA(q0, ax2[p], b0xy, q0,   MODS_X);      // + ax*x
      PK_FMA(q1, az2[p], b1zw, b1zw, MODS_Z_NW);
      PK_FMA(q1, ay2[p], b1xy, q1,   MODS_Y);
      PK_FMA(q1, ax2[p], b1xy, q1,   MODS_X);
      mq[2*p]   = fmaxf(fmaxf(q0.x, q1.x), mq[2*p]);     // v_max3_f32
      mq[2*p+1] = fmaxf(fmaxf(q0.y, q1.y), mq[2*p+1]);   // v_max3_f32
    }
  }

  // cross-wave max-combine through LDS (R3-style 16B-stride stores)
#pragma unroll
  for (int g = 0; g < 4; g++) {
    *(float4*)(red + w * PPB + g * 256 + l * 4) =
        make_float4(mq[g*4+0], mq[g*4+1], mq[g*4+2], mq[g*4+3]);
  }
  __syncthreads();
  float4 m0 = *(const float4*)(red + 0 * PPB + t * 4);
  float4 m1 = *(const float4*)(red + 1 * PPB + t * 4);
  float4 m2 = *(const float4*)(red + 2 * PPB + t * 4);
  float4 m3 = *(const float4*)(red + 3 * PPB + t * 4);
  float4 mm;
  mm.x = fmaxf(fmaxf(m0.x, m1.x), fmaxf(m2.x, m3.x));
  mm.y = fmaxf(fmaxf(m0.y, m1.y), fmaxf(m2.y, m3.y));
  mm.z = fmaxf(fmaxf(m0.z, m1.z), fmaxf(m2.z, m3.z));
  mm.w = fmaxf(fmaxf(m0.w, m1.w), fmaxf(m2.w, m3.w));

  // chunk-major partial: partial[chunk*TOTAL_A + sb*NPTS + nb*PPB + n_local]
  const int sb = side * BATCH + batch;
  float* pb = partial + (size_t)chunk * TOTAL_A + (size_t)sb * NPTS + (size_t)nb * PPB;
  *(float4*)(pb + t * 4) = mm;
}

// Fused combine + global reduce + finalize (last block writes out).
__global__ __launch_bounds__(BLK) void chamfer_pass2(
    const float* __restrict__ pred, const float* __restrict__ gt,
    const float* __restrict__ partial, float* __restrict__ acc,
    unsigned* __restrict__ counter, float* __restrict__ out) {
  const int gid  = blockIdx.x * BLK + threadIdx.x;   // [0, TOTAL_A)
  const int side = gid >> 16;                        // BATCH*NPTS == 65536
  const int rem  = gid & 65535;

  const float* A = (side == 0) ? pred : gt;
  float x = A[(size_t)rem * 3 + 0];
  float y = A[(size_t)rem * 3 + 1];
  float z = A[(size_t)rem * 3 + 2];
  float a2 = fmaf(x, x, fmaf(y, y, z * z));

  float mq = -1e30f;
#pragma unroll
  for (int c = 0; c < NCH; c++) {
    mq = fmaxf(mq, partial[(size_t)c * TOTAL_A + gid]);   // coalesced
  }
  float d2 = fmaxf(fmaf(-2.0f, mq, a2), 0.0f);

  float v = d2;
  for (int off = 32; off > 0; off >>= 1) v += __shfl_down(v, off);
  __shared__ float wsum[BLK / 64];
  int lane = threadIdx.x & 63, wv = threadIdx.x >> 6;
  if (lane == 0) wsum[wv] = v;
  __syncthreads();
  if (threadIdx.x == 0) {
    float s = wsum[0] + wsum[1] + wsum[2] + wsum[3];
    atomicAdd(acc, s);            // device-scope
    __threadfence();
    unsigned old = atomicAdd(counter, 1u);
    if (old == P2_BLOCKS - 1) {   // last block: all acc adds visible
      __threadfence();
      float total = atomicAdd(acc, 0.0f);
      out[0] = total * (1.0f / (float)TOTAL_A);  // (s1+s2)/(2*65536)
    }
  }
}

extern "C" void kernel_launch(void* const* d_in, const int* in_sizes, int n_in,
                              void* d_out, int out_size, void* d_ws, size_t ws_size,
                              hipStream_t stream) {
  const float* pred = (const float*)d_in[0];
  const float* gt   = (const float*)d_in[1];
  float* out = (float*)d_out;

  float* partial = (float*)d_ws;                       // 4.2 MB
  float* acc = partial + (size_t)TOTAL_A * NCH;        // [acc, counter]
  unsigned* counter = (unsigned*)(acc + 1);

  chamfer_pass1<<<GRID1, BLK, 0, stream>>>(pred, gt, partial, acc);
  chamfer_pass2<<<P2_BLOCKS, BLK, 0, stream>>>(pred, gt, partial, acc, counter, out);
}